// Round 9
// baseline (1271.748 us; speedup 1.0000x reference)
//
#include <hip/hip_runtime.h>
#include <hip/hip_bf16.h>

typedef __bf16 bf16;
typedef __bf16 bf16x4 __attribute__((ext_vector_type(4)));
typedef __bf16 bf16x8 __attribute__((ext_vector_type(8)));
typedef float f32x4 __attribute__((ext_vector_type(4)));

#define BB 64
#define EMB 256
#define UNITS 512
#define POI 5000
#define KCAT 1280
#define SCLD 5024   // sc row stride
#define LGLD 5008   // logits slab row stride
#define NBLK 626    // grid: guaranteed co-resident (launch_bounds(256,3) -> 3 blk/CU x 256 = 768 >= 626)
#define L2E 1.4426950408889634f

__device__ __forceinline__ float rcp_(float x){ return __builtin_amdgcn_rcpf(x); }
__device__ __forceinline__ float exp2_(float x){ return __builtin_amdgcn_exp2f(x); }

struct KArgs {
  const int* x; const float* query; const float* emb; const float* h0; const float* catd;
  const float* gruK; const float* gruR; const float* gruB;
  const float* W1; const float* W1b; const float* W2; const float* W2b; const float* Vw;
  const float* fcw; const float* fcb; float* out;
  float* outc; float* xmP; float* hmP; float* hn; float* Eq; float* sc;
  bf16* fcwT; bf16* W1T; bf16* W2T; bf16* embT;
  int* bar;
};

// ---- software grid barrier (the cg::grid_sync mechanism, plain-launch safe).
// All NBLK blocks are resident by construction, so no deadlock.
__device__ __forceinline__ void gbar(int* bar, int ph){
  __syncthreads();
  if(threadIdx.x == 0){
    __threadfence();   // release: make this block's stores device-visible
    __hip_atomic_fetch_add(&bar[ph], 1, __ATOMIC_ACQ_REL, __HIP_MEMORY_SCOPE_AGENT);
    while(__hip_atomic_load(&bar[ph], __ATOMIC_ACQUIRE, __HIP_MEMORY_SCOPE_AGENT) < NBLK)
      __builtin_amdgcn_s_sleep(8);
  }
  __syncthreads();
  __threadfence();     // acquire: invalidate L1 so post-barrier loads see remote stores
}

// ---- MFMA tile helpers (C/D: col=lane&15, row=q*4+reg; validated R3-R8) ----
__device__ __forceinline__ f32x4 mm16f(const float* __restrict__ A, const float* __restrict__ B,
                                       int lda, int ldb, int K, int mr, int nc, int lane){
  int q = lane >> 4;
  f32x4 acc = {0.f,0.f,0.f,0.f};
  const float* ap = A + (size_t)mr*lda + q*8;
  const float* bp = B + (size_t)(q*8)*ldb + nc;
#pragma unroll 2
  for(int k0 = 0; k0 < K; k0 += 32){
    f32x4 a0 = *(const f32x4*)ap;
    f32x4 a1 = *(const f32x4*)(ap+4);
    bf16x8 a, b;
#pragma unroll
    for(int j=0;j<4;j++){ a[j] = (bf16)a0[j]; a[4+j] = (bf16)a1[j]; }
#pragma unroll
    for(int j=0;j<8;j++) b[j] = (bf16)bp[(size_t)j*ldb];
    acc = __builtin_amdgcn_mfma_f32_16x16x32_bf16(a, b, acc, 0, 0, 0);
    ap += 32; bp += (size_t)32*ldb;
  }
  return acc;
}
__device__ __forceinline__ f32x4 mm16bt(const float* __restrict__ A, const bf16* __restrict__ Bt,
                                        int lda, int ldbk, int K, int mr, int nc,
                                        int ka, int kb, int lane){
  int q = lane >> 4;
  f32x4 acc = {0.f,0.f,0.f,0.f};
  const float* ap = A + (size_t)mr*lda + ka + q*8;
  const bf16* bp = Bt + (size_t)nc*ldbk + kb + q*8;
#pragma unroll 2
  for(int k0 = 0; k0 < K; k0 += 32){
    f32x4 a0 = *(const f32x4*)ap;
    f32x4 a1 = *(const f32x4*)(ap+4);
    bf16x8 a;
#pragma unroll
    for(int j=0;j<4;j++){ a[j] = (bf16)a0[j]; a[4+j] = (bf16)a1[j]; }
    bf16x8 b = *(const bf16x8*)bp;
    acc = __builtin_amdgcn_mfma_f32_16x16x32_bf16(a, b, acc, 0, 0, 0);
    ap += 32; bp += 32;
  }
  return acc;
}

__global__ __launch_bounds__(256, 3) void k_fused(KArgs a){
  __shared__ union {
    float ls[64][65];                                               // TR
    struct { float evs[16][132]; float Qs[64][68]; float vws[128]; } vs;  // VSCORE
    float red[256];                                                 // SOFTMAX
  } sm;
  int t = threadIdx.x, lane = t & 63, w = t >> 6;
  int bid = blockIdx.x;

  // ---------- P1: transpose+cvt weights (1992 jobs) + GRU GEMMs (384 jobs) ----------
  for(int j = bid; j < 2376; j += NBLK){
    if(j < 1992){
      const float* src; bf16* dst; int Ks, Ns, lddst, dRows, tn, tk;
      if(j < 1580){      src=a.fcw; Ks=1280; Ns=5000; dst=a.fcwT; lddst=1280; dRows=5008; tn=j/20; tk=j%20; }
      else if(j<1612){ int b2=j-1580; src=a.W1; Ks=256; Ns=512; dst=a.W1T; lddst=256; dRows=512; tn=b2/4; tk=b2%4; }
      else if(j<1676){ int b2=j-1612; src=a.W2; Ks=512; Ns=512; dst=a.W2T; lddst=512; dRows=512; tn=b2/8; tk=b2%8; }
      else {           int b2=j-1676; src=a.emb; Ks=5000; Ns=256; dst=a.embT; lddst=5056; dRows=256; tn=b2/79; tk=b2%79; }
      int n0 = tn*64, k0 = tk*64;
      bool fullN = (n0 + 64 <= Ns);
      __syncthreads();                       // protect ls reuse across jobs
#pragma unroll
      for(int ps=0; ps<4; ps++){
        int r = (t>>4) + ps*16;
        int sr = k0 + r; if(sr > Ks-1) sr = Ks-1;
        int c4 = (t&15)*4;
        if(fullN){
          f32x4 v = *(const f32x4*)&src[(size_t)sr*Ns + n0 + c4];
          sm.ls[r][c4]=v[0]; sm.ls[r][c4+1]=v[1]; sm.ls[r][c4+2]=v[2]; sm.ls[r][c4+3]=v[3];
        } else {
#pragma unroll
          for(int i=0;i<4;i++){ int sc2 = n0+c4+i; if(sc2 > Ns-1) sc2 = Ns-1; sm.ls[r][c4+i] = src[(size_t)sr*Ns + sc2]; }
        }
      }
      __syncthreads();
#pragma unroll
      for(int ps=0; ps<4; ps++){
        int rr = (t>>4) + ps*16;
        int dr = n0 + rr;
        if(dr < dRows){
          int cc = (t&15)*4;
          bf16x4 o;
#pragma unroll
          for(int i=0;i<4;i++) o[i] = (bf16)sm.ls[cc+i][rr];
          *(bf16x4*)&dst[(size_t)dr*lddst + k0 + cc] = o;
        }
      }
    } else {
      int g = j - 1992;                      // GRU: (96,2,2) flattened
      int bx = g % 96, rem = g / 96, by = rem & 1, z = rem >> 1;
      int col = bx*16 + (lane & 15);
      int m = w*16 + (lane & 15);
      const float* A; const float* B; int lda, mr;
      if(by == 0){
        B = a.gruK + (size_t)(z*256)*1536;
        if(z == 0){ A = a.emb;   mr = a.x[m]; lda = EMB; }
        else      { A = a.query; mr = m;      lda = 256; }
      } else {
        B = a.gruR + (size_t)(z*256)*1536;
        A = a.h0 + z*256; mr = m; lda = UNITS;
      }
      f32x4 acc = mm16f(A, B, lda, 1536, 256, mr, col, lane);
      float* C = (by ? a.hmP : a.xmP) + (size_t)z*BB*1536;
      int rb = w*16 + (lane >> 4)*4;
#pragma unroll
      for(int r=0;r<4;r++) C[(size_t)(rb+r)*1536 + col] = acc[r];
    }
  }
  gbar(a.bar, 0);

  // ---------- P2: GRU gates (64 jobs, 256 thr x 2 u-halves) ----------
  for(int b = bid; b < BB; b += NBLK){
    a.outc[b*KCAT + t] = 0.f;                // zero ctx accumulator region
    const float* x0 = a.xmP + b*1536; const float* x1s = a.xmP + (size_t)BB*1536 + b*1536;
    const float* h0s = a.hmP + b*1536; const float* h1s = a.hmP + (size_t)BB*1536 + b*1536;
#pragma unroll
    for(int ui=0; ui<2; ui++){
      int u = t + ui*256;
      float xz = x0[u]      + x1s[u]      + a.gruB[u];
      float xg = x0[512+u]  + x1s[512+u]  + a.gruB[512+u];
      float xh = x0[1024+u] + x1s[1024+u] + a.gruB[1024+u];
      float hz = h0s[u]      + h1s[u]      + a.gruB[1536+u];
      float hg = h0s[512+u]  + h1s[512+u]  + a.gruB[2048+u];
      float hh = h0s[1024+u] + h1s[1024+u] + a.gruB[2560+u];
      float z = rcp_(1.f + exp2_(-L2E*(xz+hz)));
      float r = rcp_(1.f + exp2_(-L2E*(xg+hg)));
      float ca = xh + r*hh;
      ca = fminf(fmaxf(ca, -15.f), 15.f);
      float e = exp2_(2.f*L2E*ca);
      float hc = (e - 1.f)*rcp_(e + 1.f);
      float h = a.h0[b*512+u];
      float v = z*h + (1.f - z)*hc;
      a.hn[b*512+u] = v;
      a.outc[b*KCAT + 256 + u] = v;
      a.outc[b*KCAT + 768 + u] = a.catd[(size_t)b*512 + u];
      a.out[(size_t)POI*BB + (size_t)b*512 + u] = v;                        // state
      a.out[(size_t)POI*BB + (size_t)BB*512 + (size_t)b*512 + u] = v;       // output_
    }
  }
  gbar(a.bar, 1);

  // ---------- P3: Eq = exp2(clamp(2*log2e*(hn@W2+b2))) (32 jobs) ----------
  for(int q = bid; q < 32; q += NBLK){
    int col = q*16 + (lane & 15);
    f32x4 acc = mm16bt(a.hn, a.W2T, UNITS, UNITS, UNITS, w*16 + (lane & 15), col, 0, 0, lane);
    float bn = a.W2b[col];
    int rb = w*16 + (lane >> 4)*4;
#pragma unroll
    for(int r=0;r<4;r++){
      float v = (acc[r] + bn)*(2.f*L2E);
      a.Eq[(rb+r)*UNITS + col] = exp2_(fminf(fmaxf(v, -28.f), 28.f));
    }
  }
  gbar(a.bar, 2);

  // ---------- P4: fused vproj+score (1252 jobs = exactly 2/block; R5/R8 44-VGPR shape) ----------
  for(int v = bid; v < 1252; v += NBLK){
    int px = v % 313, y = v / 313;
    int p0 = px*16, uh = y*128;
    int mr = p0 + (lane & 15); if(mr > POI-1) mr = POI-1;
    __syncthreads();                         // protect evs/Qs reuse across jobs
#pragma unroll
    for(int i=0;i<2;i++){
      int ncl = (w + i*4)*16 + (lane & 15);
      f32x4 acc = mm16bt(a.emb, a.W1T, EMB, EMB, EMB, mr, uh + ncl, 0, 0, lane);
      float bn = a.W1b[uh + ncl];
      int rb = (lane >> 4)*4;
#pragma unroll
      for(int r=0;r<4;r++){
        float vv = (acc[r] + bn)*(2.f*L2E);
        sm.vs.evs[rb+r][ncl] = exp2_(fminf(fmaxf(vv, -28.f), 28.f));
      }
    }
    if(t < 128) sm.vs.vws[t] = a.Vw[uh + t];
    int tp = t & 7, tb = t >> 3;
    float s00=0.f, s01=0.f, s10=0.f, s11=0.f;
    for(int c=0;c<2;c++){
      __syncthreads();
      int ub = c*64;
      for(int i=t;i<4096;i+=256){ int b2=i>>6, u=i&63; sm.vs.Qs[b2][u] = a.Eq[b2*UNITS + uh + ub + u]; }
      __syncthreads();
#pragma unroll
      for(int u4=0;u4<16;u4++){
        f32x4 e0 = *(f32x4*)&sm.vs.evs[2*tp][ub+u4*4];
        f32x4 e1 = *(f32x4*)&sm.vs.evs[2*tp+1][ub+u4*4];
        f32x4 q0 = *(f32x4*)&sm.vs.Qs[2*tb][u4*4];
        f32x4 q1 = *(f32x4*)&sm.vs.Qs[2*tb+1][u4*4];
        f32x4 w4 = *(f32x4*)&sm.vs.vws[ub+u4*4];
#pragma unroll
        for(int e=0;e<4;e++){
          float wv = w4[e];
          s00 += wv * rcp_(e0[e]*q0[e] + 1.f);
          s01 += wv * rcp_(e0[e]*q1[e] + 1.f);
          s10 += wv * rcp_(e1[e]*q0[e] + 1.f);
          s11 += wv * rcp_(e1[e]*q1[e] + 1.f);
        }
      }
    }
    float* s = a.sc + (size_t)y*BB*SCLD;
    int pA = p0 + 2*tp, bA = 2*tb;
    if(pA < POI)  { s[(size_t)bA*SCLD + pA]   = s00; s[(size_t)(bA+1)*SCLD + pA]   = s01; }
    if(pA+1 < POI){ s[(size_t)bA*SCLD + pA+1] = s10; s[(size_t)(bA+1)*SCLD + pA+1] = s11; }
  }
  gbar(a.bar, 3);

  // ---------- P5: softmax (64 jobs; tanh identity, SW cancels, bounded) ----------
  for(int b = bid; b < BB; b += NBLK){
    float* sA = a.sc + (size_t)b*SCLD;
    float sum = 0.f;
    for(int p=t;p<POI;p+=256){
      float acc = sA[p] + sA[(size_t)BB*SCLD + p] + sA[(size_t)2*BB*SCLD + p] + sA[(size_t)3*BB*SCLD + p];
      float wv = exp2_(-2.f*L2E*acc);
      sA[p] = wv;
      sum += wv;
    }
    __syncthreads();                          // protect red reuse
    sm.red[t] = sum; __syncthreads();
    for(int o=128;o>0;o>>=1){ if(t<o) sm.red[t]+=sm.red[t+o]; __syncthreads(); }
    float iv = rcp_(sm.red[0]);
    for(int p=t;p<POI;p+=256) sA[p] *= iv;
    if(t < SCLD-POI) sA[POI + t] = 0.f;       // zero k-pad for ctx GEMM
  }
  gbar(a.bar, 4);

  // ---------- P6: context = w @ emb via embT (208 jobs, atomics into outc) ----------
  for(int c = bid; c < 208; c += NBLK){
    int bx = c & 15, ky = c >> 4;
    int n = bx*16 + (lane & 15);
    int kbeg = ky*384, kk = (ky == 12) ? 416 : 384;
    f32x4 acc = mm16bt(a.sc, a.embT, SCLD, 5056, kk, w*16 + (lane & 15), n, kbeg, kbeg, lane);
    int rb = w*16 + (lane >> 4)*4;
#pragma unroll
    for(int r=0;r<4;r++) atomicAdd(&a.outc[(size_t)(rb+r)*KCAT + n], acc[r]);
  }
  gbar(a.bar, 5);

  // ---------- P7: logits split-K x2 into slabs (626 jobs = 1/block) ----------
  {
    float* lgP = a.sc + (size_t)BB*SCLD;      // slabs 1-2 of sc are dead after softmax
    for(int l = bid; l < 626; l += NBLK){
      int nt = l % 313, ky = l / 313;
      int n = nt*16 + (lane & 15);
      int kbeg = ky*640;
      f32x4 acc = mm16bt(a.outc, a.fcwT, KCAT, 1280, 640, w*16 + (lane & 15), n, kbeg, kbeg, lane);
      float* dst = lgP + (size_t)ky*BB*SCLD;
      int rb = w*16 + (lane >> 4)*4;
#pragma unroll
      for(int r=0;r<4;r++) dst[(size_t)(rb+r)*LGLD + n] = acc[r];
    }
  }
  gbar(a.bar, 6);

  // ---------- P8: out = lg0 + lg1 + fcb (313 jobs) ----------
  {
    const float* lgP = a.sc + (size_t)BB*SCLD;
    for(int rj = bid; rj < 313; rj += NBLK){
      int idx = rj*256 + t;
      int m = idx / 1252, nq = idx % 1252;
      int n = nq*4;
      if(n < POI){
        f32x4 va = *(const f32x4*)&lgP[(size_t)m*LGLD + n];
        f32x4 vb = *(const f32x4*)&lgP[(size_t)BB*SCLD + (size_t)m*LGLD + n];
        f32x4 vc = *(const f32x4*)&a.fcb[n];
        f32x4 r = va + vb + vc;
        *(f32x4*)&a.out[(size_t)m*POI + n] = r;
      }
    }
  }
}

extern "C" void kernel_launch(void* const* d_in, const int* in_sizes, int n_in,
                              void* d_out, int out_size, void* d_ws, size_t ws_size,
                              hipStream_t stream){
  KArgs a;
  a.x     = (const int*)d_in[0];
  a.query = (const float*)d_in[1];
  a.emb   = (const float*)d_in[2];
  // d_in[3] A_hat unused by reference
  a.h0    = (const float*)d_in[4];
  a.catd  = (const float*)d_in[5];
  a.gruK  = (const float*)d_in[6];
  a.gruR  = (const float*)d_in[7];
  a.gruB  = (const float*)d_in[8];
  a.W1    = (const float*)d_in[9];
  a.W1b   = (const float*)d_in[10];
  a.W2    = (const float*)d_in[11];
  a.W2b   = (const float*)d_in[12];
  a.Vw    = (const float*)d_in[13];
  // d_in[14] V_b: softmax-invariant, dropped
  a.fcw   = (const float*)d_in[15];
  a.fcb   = (const float*)d_in[16];
  a.out   = (float*)d_out;

  char* ws = (char*)d_ws;
  size_t off = 0;
  auto alloc = [&](size_t bytes)->void*{ void* p = ws + off; off += (bytes + 255) & ~(size_t)255; return p; };
  a.bar  = (int*)  alloc(64);
  a.outc = (float*)alloc((size_t)BB*KCAT*4);
  a.xmP  = (float*)alloc((size_t)2*BB*1536*4);
  a.hmP  = (float*)alloc((size_t)2*BB*1536*4);
  a.hn   = (float*)alloc((size_t)BB*512*4);
  a.Eq   = (float*)alloc((size_t)BB*512*4);
  a.sc   = (float*)alloc((size_t)4*BB*SCLD*4);   // 4 vscore slabs; 1-2 reused as logits partials
  a.fcwT = (bf16*)alloc((size_t)5008*1280*2);
  a.W1T  = (bf16*)alloc((size_t)512*256*2);
  a.W2T  = (bf16*)alloc((size_t)512*512*2);
  a.embT = (bf16*)alloc((size_t)256*5056*2);
  // total ~24 MB

  hipMemsetAsync(a.bar, 0, 64, stream);          // zero barrier counters (ws is poisoned 0xAA)
  k_fused<<<NBLK, 256, 0, stream>>>(a);
}

// Round 10
// 214.298 us; speedup vs baseline: 5.9345x; 5.9345x over previous
//
#include <hip/hip_runtime.h>
#include <hip/hip_bf16.h>

typedef __bf16 bf16;
typedef __bf16 bf16x4 __attribute__((ext_vector_type(4)));
typedef __bf16 bf16x8 __attribute__((ext_vector_type(8)));
typedef float f32x4 __attribute__((ext_vector_type(4)));

#define BB 64
#define EMB 256
#define UNITS 512
#define POI 5000
#define KCAT 1280
#define SCLD 5024   // sc row stride (5000 padded to x32)
#define L2E 1.4426950408889634f

__device__ __forceinline__ float rcp_(float x){ return __builtin_amdgcn_rcpf(x); }
__device__ __forceinline__ float exp2_(float x){ return __builtin_amdgcn_exp2f(x); }

// ---- 16x16 MFMA C-tile: A fp32 row-major (cvt->bf16), B fp32 row-major (scalar gather).
__device__ __forceinline__ f32x4 mm16f(const float* __restrict__ A, const float* __restrict__ B,
                                       int lda, int ldb, int K, int mr, int nc, int lane){
  int q = lane >> 4;
  f32x4 acc = {0.f,0.f,0.f,0.f};
  const float* ap = A + (size_t)mr*lda + q*8;
  const float* bp = B + (size_t)(q*8)*ldb + nc;
#pragma unroll 2
  for(int k0 = 0; k0 < K; k0 += 32){
    f32x4 a0 = *(const f32x4*)ap;
    f32x4 a1 = *(const f32x4*)(ap+4);
    bf16x8 a, b;
#pragma unroll
    for(int j=0;j<4;j++){ a[j] = (bf16)a0[j]; a[4+j] = (bf16)a1[j]; }
#pragma unroll
    for(int j=0;j<8;j++) b[j] = (bf16)bp[(size_t)j*ldb];
    acc = __builtin_amdgcn_mfma_f32_16x16x32_bf16(a, b, acc, 0, 0, 0);
    ap += 32; bp += (size_t)32*ldb;
  }
  return acc;
}
// ---- B pre-transposed bf16 Bt[n][k] -> contiguous 16B B-fragment load.
__device__ __forceinline__ f32x4 mm16bt(const float* __restrict__ A, const bf16* __restrict__ Bt,
                                        int lda, int ldbk, int K, int mr, int nc,
                                        int ka, int kb, int lane){
  int q = lane >> 4;
  f32x4 acc = {0.f,0.f,0.f,0.f};
  const float* ap = A + (size_t)mr*lda + ka + q*8;
  const bf16* bp = Bt + (size_t)nc*ldbk + kb + q*8;
#pragma unroll 2
  for(int k0 = 0; k0 < K; k0 += 32){
    f32x4 a0 = *(const f32x4*)ap;
    f32x4 a1 = *(const f32x4*)(ap+4);
    bf16x8 a;
#pragma unroll
    for(int j=0;j<4;j++){ a[j] = (bf16)a0[j]; a[4+j] = (bf16)a1[j]; }
    bf16x8 b = *(const bf16x8*)bp;
    acc = __builtin_amdgcn_mfma_f32_16x16x32_bf16(a, b, acc, 0, 0, 0);
    ap += 32; bp += 32;
  }
  return acc;
}

// ---- merged: transpose+cvt (jobs 0..2375, R8 k_tr verbatim) + GRU GEMMs (2376..2759).
__global__ __launch_bounds__(256) void k_trgru(const float* __restrict__ fcw, const float* __restrict__ gruK,
    const float* __restrict__ gruR, const float* __restrict__ W1, const float* __restrict__ W2,
    const float* __restrict__ emb, bf16* __restrict__ fcwT, bf16* __restrict__ gKT,
    bf16* __restrict__ gRT, bf16* __restrict__ W1T, bf16* __restrict__ W2T, bf16* __restrict__ embT,
    const int* __restrict__ x, const float* __restrict__ query, const float* __restrict__ h0,
    float* __restrict__ xmP, float* __restrict__ hmP){
  int bid = blockIdx.x, t = threadIdx.x;
  if(bid < 2376){
    __shared__ float ls[64][65];
    const float* src; bf16* dst; int Ks, Ns, lddst, dRows, tn, tk;
    if(bid < 1580){      src=fcw;  Ks=1280; Ns=5000; dst=fcwT; lddst=1280; dRows=5008; tn=bid/20; tk=bid%20; }
    else if(bid < 1772){ int b=bid-1580; src=gruK; Ks=512; Ns=1536; dst=gKT; lddst=512; dRows=1536; tn=b/8; tk=b%8; }
    else if(bid < 1964){ int b=bid-1772; src=gruR; Ks=512; Ns=1536; dst=gRT; lddst=512; dRows=1536; tn=b/8; tk=b%8; }
    else if(bid < 1996){ int b=bid-1964; src=W1;   Ks=256; Ns=512;  dst=W1T; lddst=256; dRows=512;  tn=b/4; tk=b%4; }
    else if(bid < 2060){ int b=bid-1996; src=W2;   Ks=512; Ns=512;  dst=W2T; lddst=512; dRows=512;  tn=b/8; tk=b%8; }
    else {               int b=bid-2060; src=emb;  Ks=5000; Ns=256; dst=embT; lddst=5056; dRows=256; tn=b/79; tk=b%79; }
    int n0 = tn*64, k0 = tk*64;
    bool fullN = (n0 + 64 <= Ns);
#pragma unroll
    for(int ps=0; ps<4; ps++){
      int r = (t>>4) + ps*16;
      int sr = k0 + r; if(sr > Ks-1) sr = Ks-1;
      int c4 = (t&15)*4;
      if(fullN){
        f32x4 v = *(const f32x4*)&src[(size_t)sr*Ns + n0 + c4];
        ls[r][c4]=v[0]; ls[r][c4+1]=v[1]; ls[r][c4+2]=v[2]; ls[r][c4+3]=v[3];
      } else {
#pragma unroll
        for(int i=0;i<4;i++){ int sc2 = n0+c4+i; if(sc2 > Ns-1) sc2 = Ns-1; ls[r][c4+i] = src[(size_t)sr*Ns + sc2]; }
      }
    }
    __syncthreads();
#pragma unroll
    for(int ps=0; ps<4; ps++){
      int rr = (t>>4) + ps*16;
      int dr = n0 + rr;
      if(dr < dRows){
        int cc = (t&15)*4;
        bf16x4 o;
#pragma unroll
        for(int i=0;i<4;i++) o[i] = (bf16)ls[cc+i][rr];
        *(bf16x4*)&dst[(size_t)dr*lddst + k0 + cc] = o;
      }
    }
  } else {
    int g = bid - 2376;                    // GRU: (96,2,2) flattened; B from fp32 (gKT not ready)
    int lane = t & 63, w = t >> 6;
    int bx = g % 96, rem = g / 96, by = rem & 1, z = rem >> 1;
    int col = bx*16 + (lane & 15);
    int m = w*16 + (lane & 15);
    const float* A; const float* B; int lda, mr;
    if(by == 0){
      B = gruK + (size_t)(z*256)*1536;
      if(z == 0){ A = emb;   mr = x[m]; lda = EMB; }
      else      { A = query; mr = m;    lda = 256; }
    } else {
      B = gruR + (size_t)(z*256)*1536;
      A = h0 + z*256; mr = m; lda = UNITS;
    }
    f32x4 acc = mm16f(A, B, lda, 1536, 256, mr, col, lane);
    float* C = (by ? hmP : xmP) + (size_t)z*BB*1536;
    int rb = w*16 + (lane >> 4)*4;
#pragma unroll
    for(int r=0;r<4;r++) C[(size_t)(rb+r)*1536 + col] = acc[r];
  }
}

// ---- GRU gates; sums 2 k-split slabs; copies cat_dec; zeroes d_out logits row b (for atomics).
__global__ void k_gates(const float* __restrict__ xmP, const float* __restrict__ hmP,
                        const float* __restrict__ bias, const float* __restrict__ h0,
                        const float* __restrict__ catd,
                        float* __restrict__ hn, float* __restrict__ outc, float* __restrict__ dout){
  int b = blockIdx.x, u = threadIdx.x;  // 512 thr
  for(int p=u;p<POI;p+=512) dout[(size_t)b*POI + p] = 0.f;
  const float* x0 = xmP + b*1536; const float* x1s = xmP + (size_t)BB*1536 + b*1536;
  const float* h0s = hmP + b*1536; const float* h1s = hmP + (size_t)BB*1536 + b*1536;
  float xz = x0[u]      + x1s[u]      + bias[u];
  float xg = x0[512+u]  + x1s[512+u]  + bias[512+u];
  float xh = x0[1024+u] + x1s[1024+u] + bias[1024+u];
  float hz = h0s[u]      + h1s[u]      + bias[1536+u];
  float hg = h0s[512+u]  + h1s[512+u]  + bias[2048+u];
  float hh = h0s[1024+u] + h1s[1024+u] + bias[2560+u];
  float z = rcp_(1.f + exp2_(-L2E*(xz+hz)));
  float r = rcp_(1.f + exp2_(-L2E*(xg+hg)));
  float ca = xh + r*hh;
  ca = fminf(fmaxf(ca, -15.f), 15.f);
  float e = exp2_(2.f*L2E*ca);
  float hc = (e - 1.f)*rcp_(e + 1.f);
  float h = h0[b*512+u];
  float v = z*h + (1.f - z)*hc;
  hn[b*512+u] = v;
  outc[b*KCAT + 256 + u] = v;
  outc[b*KCAT + 768 + u] = catd[(size_t)b*512 + u];
  dout[(size_t)POI*BB + (size_t)b*512 + u] = v;                       // state
  dout[(size_t)POI*BB + (size_t)BB*512 + (size_t)b*512 + u] = v;      // output_
}

// ---- Eq = exp2(clamp(2*log2e*(hn@W2 + b2), +-28)). grid 128 x 64thr.
__global__ __launch_bounds__(64) void k_qproj(const float* __restrict__ hn, const bf16* __restrict__ W2T,
                        const float* __restrict__ W2b, float* __restrict__ Eq){
  int lane = threadIdx.x;
  int m0 = (blockIdx.x & 3)*16;
  int col = (blockIdx.x >> 2)*16 + (lane & 15);
  f32x4 acc = mm16bt(hn, W2T, UNITS, UNITS, UNITS, m0 + (lane & 15), col, 0, 0, lane);
  float bn = W2b[col];
  int rb = m0 + (lane >> 4)*4;
#pragma unroll
  for(int r=0;r<4;r++){
    float v = (acc[r] + bn)*(2.f*L2E);
    Eq[(rb+r)*UNITS + col] = exp2_(fminf(fmaxf(v, -28.f), 28.f));
  }
}

// ---- fused vproj+score. R8 chunk structure (44-VGPR proven) + 2-way rcp pairing:
// w0/d0 + w1/d1 = (w0*d1 + w1*d0) * rcp(d0*d1)  -> 8 rcp per u4 instead of 16.
// GUARD: if VGPR_Count > 100 in profile, revert pairing (R6/R7 lesson).
__global__ __launch_bounds__(256) void k_vscore(const float* __restrict__ emb, const bf16* __restrict__ W1T,
    const float* __restrict__ W1b, const float* __restrict__ Eq,
    const float* __restrict__ Vw, float* __restrict__ scS){
  __shared__ float evs[16][132];
  __shared__ float Qs[64][68];
  __shared__ float vws[128];
  int t = threadIdx.x, lane = t & 63, w = t >> 6;
  int p0 = blockIdx.x*16, uh = blockIdx.y*128;
  int mr = p0 + (lane & 15); if(mr > POI-1) mr = POI-1;   // tail clamp
#pragma unroll
  for(int i=0;i<2;i++){
    int ncl = (w + i*4)*16 + (lane & 15);
    f32x4 acc = mm16bt(emb, W1T, EMB, EMB, EMB, mr, uh + ncl, 0, 0, lane);
    float bn = W1b[uh + ncl];
    int rb = (lane >> 4)*4;
#pragma unroll
    for(int r=0;r<4;r++){
      float v = (acc[r] + bn)*(2.f*L2E);
      evs[rb+r][ncl] = exp2_(fminf(fmaxf(v, -28.f), 28.f));
    }
  }
  if(t < 128) vws[t] = Vw[uh + t];
  int tp = t & 7, tb = t >> 3;
  float s00=0.f, s01=0.f, s10=0.f, s11=0.f;
  for(int c=0;c<2;c++){
    __syncthreads();                 // c=0: evs/vws complete; c=1: Qs consumers done
    int ub = c*64;
    for(int i=t;i<4096;i+=256){ int b=i>>6, u=i&63; Qs[b][u] = Eq[b*UNITS + uh + ub + u]; }
    __syncthreads();
#pragma unroll
    for(int u4=0;u4<16;u4++){
      f32x4 e0 = *(f32x4*)&evs[2*tp][ub+u4*4];
      f32x4 e1 = *(f32x4*)&evs[2*tp+1][ub+u4*4];
      f32x4 q0 = *(f32x4*)&Qs[2*tb][u4*4];
      f32x4 q1 = *(f32x4*)&Qs[2*tb+1][u4*4];
      f32x4 w4 = *(f32x4*)&vws[ub+u4*4];
#pragma unroll
      for(int h=0;h<2;h++){          // u-pairs (0,1),(2,3)
        int i0 = 2*h, i1 = i0+1;
        float w0 = w4[i0], w1 = w4[i1];
        float da, db;
        da = __builtin_fmaf(e0[i0], q0[i0], 1.f); db = __builtin_fmaf(e0[i1], q0[i1], 1.f);
        s00 = __builtin_fmaf(__builtin_fmaf(w0, db, w1*da), rcp_(da*db), s00);
        da = __builtin_fmaf(e0[i0], q1[i0], 1.f); db = __builtin_fmaf(e0[i1], q1[i1], 1.f);
        s01 = __builtin_fmaf(__builtin_fmaf(w0, db, w1*da), rcp_(da*db), s01);
        da = __builtin_fmaf(e1[i0], q0[i0], 1.f); db = __builtin_fmaf(e1[i1], q0[i1], 1.f);
        s10 = __builtin_fmaf(__builtin_fmaf(w0, db, w1*da), rcp_(da*db), s10);
        da = __builtin_fmaf(e1[i0], q1[i0], 1.f); db = __builtin_fmaf(e1[i1], q1[i1], 1.f);
        s11 = __builtin_fmaf(__builtin_fmaf(w0, db, w1*da), rcp_(da*db), s11);
      }
    }
  }
  float* s = scS + (size_t)blockIdx.y*BB*SCLD;
  int pA = p0 + 2*tp, bA = 2*tb;
  if(pA < POI)  { s[(size_t)bA*SCLD + pA]   = s00; s[(size_t)(bA+1)*SCLD + pA]   = s01; }
  if(pA+1 < POI){ s[(size_t)bA*SCLD + pA+1] = s10; s[(size_t)(bA+1)*SCLD + pA+1] = s11; }
}

// ---- per-b: a = sum_y sc_y; w = exp2(-2*L2E*a); normalize into slab0; zero pad + outc ctx region.
__global__ __launch_bounds__(1024) void k_softmax(float* __restrict__ sc, float* __restrict__ outc){
  __shared__ float red[1024];
  int b = blockIdx.x, t = threadIdx.x;
  if(t < 256) outc[b*KCAT + t] = 0.f;
  float* sA = sc + (size_t)b*SCLD;
  float sum = 0.f;
  for(int p=t;p<POI;p+=1024){
    float a = sA[p] + sA[(size_t)BB*SCLD + p] + sA[(size_t)2*BB*SCLD + p] + sA[(size_t)3*BB*SCLD + p];
    float wv = exp2_(-2.f*L2E*a);
    sA[p] = wv;
    sum += wv;
  }
  red[t] = sum; __syncthreads();
  for(int o=512;o>0;o>>=1){ if(t<o) red[t]+=red[t+o]; __syncthreads(); }
  float iv = rcp_(red[0]);
  for(int p=t;p<POI;p+=1024) sA[p] *= iv;
  if(t < SCLD-POI) sA[POI + t] = 0.f;
}

// ---- context = wb[64,5024] @ emb via embT. grid (16,13), atomics into outc[:,0:256].
__global__ __launch_bounds__(256) void k_ctx(const float* __restrict__ wb, const bf16* __restrict__ embT,
                                             float* __restrict__ outc){
  int lane = threadIdx.x & 63, w = threadIdx.x >> 6;
  int n = blockIdx.x*16 + (lane & 15);
  int ky = blockIdx.y;
  int kbeg = ky*384, kk = (ky == 12) ? 416 : 384;
  f32x4 acc = mm16bt(wb, embT, SCLD, 5056, kk, w*16 + (lane & 15), n, kbeg, kbeg, lane);
  int rb = w*16 + (lane >> 4)*4;
#pragma unroll
  for(int r=0;r<4;r++) atomicAdd(&outc[(size_t)(rb+r)*KCAT + n], acc[r]);
}

// ---- logits: split-K x2, atomicAdd into d_out (rows zeroed by k_gates); bias in ky0. grid (313,2).
__global__ __launch_bounds__(256) void k_logits(const float* __restrict__ A, const bf16* __restrict__ fcwT,
                        const float* __restrict__ fcb, float* __restrict__ out){
  int lane = threadIdx.x & 63, w = threadIdx.x >> 6;
  int n = blockIdx.x*16 + (lane & 15);
  int nc = n < POI ? n : POI-1;
  int ky = blockIdx.y, kbeg = ky*640;
  f32x4 acc = mm16bt(A, fcwT, KCAT, 1280, 640, w*16 + (lane & 15), nc, kbeg, kbeg, lane);
  int rb = w*16 + (lane >> 4)*4;
  if(n < POI){
    float bn = (ky == 0) ? fcb[n] : 0.f;
#pragma unroll
    for(int r=0;r<4;r++) atomicAdd(&out[(size_t)(rb+r)*POI + n], acc[r] + bn);
  }
}

extern "C" void kernel_launch(void* const* d_in, const int* in_sizes, int n_in,
                              void* d_out, int out_size, void* d_ws, size_t ws_size,
                              hipStream_t stream){
  const int*   x     = (const int*)d_in[0];
  const float* query = (const float*)d_in[1];
  const float* emb   = (const float*)d_in[2];
  // d_in[3] A_hat unused by reference
  const float* h0    = (const float*)d_in[4];
  const float* catd  = (const float*)d_in[5];
  const float* gruK  = (const float*)d_in[6];
  const float* gruR  = (const float*)d_in[7];
  const float* gruB  = (const float*)d_in[8];
  const float* W1    = (const float*)d_in[9];
  const float* W1b   = (const float*)d_in[10];
  const float* W2    = (const float*)d_in[11];
  const float* W2b   = (const float*)d_in[12];
  const float* Vw    = (const float*)d_in[13];
  // d_in[14] V_b: softmax-invariant, dropped
  const float* fcw   = (const float*)d_in[15];
  const float* fcb   = (const float*)d_in[16];
  float* out = (float*)d_out;

  char* ws = (char*)d_ws;
  size_t off = 0;
  auto alloc = [&](size_t bytes)->void*{ void* p = ws + off; off += (bytes + 255) & ~(size_t)255; return p; };
  float* outc = (float*)alloc((size_t)BB*KCAT*4);
  float* xmP  = (float*)alloc((size_t)2*BB*1536*4);
  float* hmP  = (float*)alloc((size_t)2*BB*1536*4);
  float* hn   = (float*)alloc((size_t)BB*512*4);
  float* Eq   = (float*)alloc((size_t)BB*512*4);
  float* sc   = (float*)alloc((size_t)4*BB*SCLD*4);   // 4 u-quarter slabs
  bf16* fcwT  = (bf16*)alloc((size_t)5008*1280*2);
  bf16* gKT   = (bf16*)alloc((size_t)1536*512*2);     // produced by k_trgru, unused downstream (kept for layout stability)
  bf16* gRT   = (bf16*)alloc((size_t)1536*512*2);
  bf16* W1T   = (bf16*)alloc((size_t)512*256*2);
  bf16* W2T   = (bf16*)alloc((size_t)512*512*2);
  bf16* embT  = (bf16*)alloc((size_t)256*5056*2);
  // total ~26.6 MB (proven safe R8)

  k_trgru  <<<2760, 256, 0, stream>>>(fcw, gruK, gruR, W1, W2, emb, fcwT, gKT, gRT, W1T, W2T, embT,
                                      x, query, h0, xmP, hmP);
  k_gates  <<<BB, 512, 0, stream>>>(xmP, hmP, gruB, h0, catd, hn, outc, out);
  k_qproj  <<<128, 64, 0, stream>>>(hn, W2T, W2b, Eq);
  k_vscore <<<dim3(313,4), 256, 0, stream>>>(emb, W1T, W1b, Eq, Vw, sc);
  k_softmax<<<BB, 1024, 0, stream>>>(sc, outc);
  k_ctx    <<<dim3(16,13), 256, 0, stream>>>(sc, embT, outc);
  k_logits <<<dim3(313,2), 256, 0, stream>>>(outc, fcwT, fcb, out);
}